// Round 7
// baseline (224.354 us; speedup 1.0000x reference)
//
#include <hip/hip_runtime.h>

// Problem constants (fixed by reference setup_inputs)
#define N_PRE 8192
#define N_CUR 16384
#define KNN   8

// Workspace layout (bytes):
//   [0,      64K) : c2p  u32[N_CUR]      nearest-pre index per cur point
//   [64K,   320K) : top8 u32[N_PRE*8]    per-pre 8 nearest cur indices
//   [320K,  448K) : pre4 float4[N_PRE]   (-2px, -2py, -2pz, |p|^2)
//   [448K,  704K) : cur4 float4[N_CUR]   ( cx,   cy,   cz,  |c|^2)
//
// Comparator trick: ordering by true sqdist (fixed query) == ordering by
// (|cand|^2 - 2 cand.q) -> 3 FMA/pair. Can be negative -> monotone key map.
//
// Round-7 structure: segment-min fast path (branch-free, 8 pipelined
// ds_read_b128 per 512-candidate segment, 1 fminf per pair per query) +
// wave-uniform replay of fired segments only. A(1-NN) and B(8-NN) fused in
// one dispatch (independent roles); tiny kernel C applies mask+sqrt+mean.

#define MAPPED_INF 0xFF800000u  // monotone key of +inf (empty-slot sentinel)
#define A_BLOCKS 512            // 32 cur queries per block (4 waves x Q=8)
#define B_BLOCKS 256            // 32 pre queries per block (4 waves x P=8)

__device__ __forceinline__ unsigned key_of(float d) {
    unsigned b = __float_as_uint(d);
    return b ^ (0x80000000u | (unsigned)((int)b >> 31));
}
__device__ __forceinline__ float float_of_key(unsigned k) {
    unsigned b = (k & 0x80000000u) ? (k ^ 0x80000000u) : ~k;
    return __uint_as_float(b);
}
__device__ __forceinline__ unsigned shfl_u32(unsigned x, int src) {
    return (unsigned)__shfl((int)x, src);
}
__device__ __forceinline__ unsigned shfl_up1_u32(unsigned x) {
    return (unsigned)__shfl_up((int)x, 1);
}

// ---------- prep: pack comparator-form coords ----------
__global__ __launch_bounds__(256) void prep_kernel(
        const float* __restrict__ pre, const float* __restrict__ cur,
        float4* __restrict__ pre4, float4* __restrict__ cur4) {
    int i = blockIdx.x * 256 + threadIdx.x;
    if (i < N_CUR) {
        float x = cur[i], y = cur[N_CUR + i], z = cur[2 * N_CUR + i];
        cur4[i] = make_float4(x, y, z, fmaf(x, x, fmaf(y, y, z * z)));
    }
    if (i < N_PRE) {
        float x = pre[i], y = pre[N_PRE + i], z = pre[2 * N_PRE + i];
        pre4[i] = make_float4(-2.f * x, -2.f * y, -2.f * z,
                              fmaf(x, x, fmaf(y, y, z * z)));
    }
}

// ---------- fused A+B ----------
#define TILE 2048   // float4 elems staged in LDS (32 KB)
#define SEG  512    // candidates per segment (8 batches of 64)

__global__ __launch_bounds__(256, 3) void fused_kernel(
        const float4* __restrict__ pre4, const float4* __restrict__ cur4,
        unsigned* __restrict__ c2p, unsigned* __restrict__ top8) {
    __shared__ float4 sp[TILE];
    const int tid  = threadIdx.x;
    const int lane = tid & 63;
    const int w    = tid >> 6;                  // 0..3

    if (blockIdx.x < A_BLOCKS) {
        // ================= role A: cur2pre argmin, Q=8 =================
        const int j0 = blockIdx.x * 32 + w * 8;
        float4 cq[8];
#pragma unroll
        for (int q = 0; q < 8; ++q) cq[q] = cur4[j0 + q];

        float tq[8];
        unsigned long long bv[8];
#pragma unroll
        for (int q = 0; q < 8; ++q) {
            tq[q] = __int_as_float(0x7F800000); bv[q] = ~0ull;
        }

        for (int tile = 0; tile < N_PRE; tile += TILE) {
            __syncthreads();
            for (int k = tid; k < TILE; k += 256) sp[k] = pre4[tile + k];
            __syncthreads();

            for (int s = 0; s < TILE; s += SEG) {
                float sm[8];
#pragma unroll
                for (int q = 0; q < 8; ++q) sm[q] = __int_as_float(0x7F800000);
                // branch-free fast path: 8 pipelined reads, fmin folds
#pragma unroll
                for (int k = 0; k < 8; ++k) {
                    float4 p = sp[s + (k << 6) + lane];
#pragma unroll
                    for (int q = 0; q < 8; ++q) {
                        float d = fmaf(p.x, cq[q].x,
                                  fmaf(p.y, cq[q].y,
                                  fmaf(p.z, cq[q].z, p.w)));
                        sm[q] = fminf(sm[q], d);
                    }
                }
                unsigned long long m[8];
#pragma unroll
                for (int q = 0; q < 8; ++q) m[q] = __ballot(sm[q] < tq[q]);
                unsigned long long anym = 0;
#pragma unroll
                for (int q = 0; q < 8; ++q) anym |= m[q];

                if (anym) {   // replay fired segment (wave-uniform branch)
#pragma unroll
                    for (int k = 0; k < 8; ++k) {
                        float4 p = sp[s + (k << 6) + lane];
                        unsigned idx = (unsigned)(tile + s + (k << 6) + lane);
#pragma unroll
                        for (int q = 0; q < 8; ++q) {
                            if (m[q]) {
                                float d = fmaf(p.x, cq[q].x,
                                          fmaf(p.y, cq[q].y,
                                          fmaf(p.z, cq[q].z, p.w)));
                                unsigned long long mm = __ballot(d < tq[q]);
                                if (mm) {
                                    unsigned long long v =
                                        (((unsigned long long)key_of(d)) << 32) | idx;
#pragma unroll
                                    for (int off = 32; off > 0; off >>= 1) {
                                        unsigned long long o =
                                            __shfl_xor((unsigned long long)v, off);
                                        v = (o < v) ? o : v;
                                    }
                                    if (v < bv[q]) {
                                        bv[q] = v;
                                        tq[q] = float_of_key((unsigned)(v >> 32));
                                    }
                                }
                            }
                        }
                    }
                }
            }
        }
#pragma unroll
        for (int q = 0; q < 8; ++q)
            if (lane == 0) c2p[j0 + q] = (unsigned)(bv[q] & 0xFFFFFFFFull);

    } else {
        // ================= role B: per-pre top-8, P=8 =================
        const int i0 = (blockIdx.x - A_BLOCKS) * 32 + w * 8;
        float4 pq[8];
#pragma unroll
        for (int q = 0; q < 8; ++q) pq[q] = pre4[i0 + q];   // (-2p, |p|^2)

        unsigned ld[8], li[8];
        float t8[8];
#pragma unroll
        for (int q = 0; q < 8; ++q) {
            ld[q] = MAPPED_INF; li[q] = 0u; t8[q] = __int_as_float(0x7F800000);
        }

        for (int tile = 0; tile < N_CUR; tile += TILE) {
            __syncthreads();
            for (int k = tid; k < TILE; k += 256) sp[k] = cur4[tile + k];
            __syncthreads();

            for (int s = 0; s < TILE; s += SEG) {
                float sm[8];
#pragma unroll
                for (int q = 0; q < 8; ++q) sm[q] = __int_as_float(0x7F800000);
#pragma unroll
                for (int k = 0; k < 8; ++k) {
                    float4 c = sp[s + (k << 6) + lane];
#pragma unroll
                    for (int q = 0; q < 8; ++q) {
                        float d = fmaf(pq[q].x, c.x,
                                  fmaf(pq[q].y, c.y,
                                  fmaf(pq[q].z, c.z, c.w)));
                        sm[q] = fminf(sm[q], d);
                    }
                }
                unsigned long long m[8];
#pragma unroll
                for (int q = 0; q < 8; ++q) m[q] = __ballot(sm[q] < t8[q]);
                unsigned long long anym = 0;
#pragma unroll
                for (int q = 0; q < 8; ++q) anym |= m[q];

                if (anym) {   // replay fired segment
#pragma unroll
                    for (int k = 0; k < 8; ++k) {
                        float4 c = sp[s + (k << 6) + lane];
                        unsigned base = (unsigned)(tile + s + (k << 6));
#pragma unroll
                        for (int q = 0; q < 8; ++q) {
                            if (m[q]) {
                                float d = fmaf(pq[q].x, c.x,
                                          fmaf(pq[q].y, c.y,
                                          fmaf(pq[q].z, c.z, c.w)));
                                unsigned long long mm = __ballot(d < t8[q]);
                                while (mm) {   // ascending-idx shift-insert
                                    int src = __ffsll((long long)mm) - 1;
                                    unsigned kd = key_of(__uint_as_float(
                                        shfl_u32(__float_as_uint(d), src)));
                                    unsigned kj = base + (unsigned)src;
                                    unsigned ud = shfl_up1_u32(ld[q]);
                                    unsigned uj = shfl_up1_u32(li[q]);
                                    if (lane == 0) ud = 0u;
                                    bool hi = kd < ud, lo = kd < ld[q];
                                    ld[q] = hi ? ud : (lo ? kd : ld[q]);
                                    li[q] = hi ? uj : (lo ? kj : li[q]);
                                    t8[q] = float_of_key(shfl_u32(ld[q], 7));
                                    mm = (mm & (mm - 1)) & __ballot(d < t8[q]);
                                }
                            }
                        }
                    }
                }
            }
        }
        // lists live on lanes 0..7, ascending
#pragma unroll
        for (int q = 0; q < 8; ++q)
            if (lane < 8) top8[(i0 + q) * 8 + lane] = li[q];
    }
}

// ---------- kernel C: mask + sqrt + mean ----------
// thread per (pre, k): 65536 threads; 8 consecutive lanes per pre point.
__global__ __launch_bounds__(256) void finalize_kernel(
        const float4* __restrict__ pre4, const float4* __restrict__ cur4,
        const float* __restrict__ ups,
        const unsigned* __restrict__ c2p, const unsigned* __restrict__ top8,
        float* __restrict__ out) {
    int gid = blockIdx.x * 256 + threadIdx.x;
    int i = gid >> 3;
    unsigned j = top8[gid];
    float4 c = cur4[j];
    float4 p = pre4[i];
    float px = -0.5f * p.x, py = -0.5f * p.y, pz = -0.5f * p.z;  // exact
    float dx = c.x - px, dy = c.y - py, dz = c.z - pz;
    float dsq = fmaf(dx, dx, fmaf(dy, dy, dz * dz));
    float v = (c2p[j] == (unsigned)i) ? sqrtf(dsq) : 0.f;
    v += __shfl_xor(v, 1);
    v += __shfl_xor(v, 2);
    v += __shfl_xor(v, 4);
    if ((gid & 7) == 0) out[i] = v / ups[i];
}

// ---------- launch ----------
extern "C" void kernel_launch(void* const* d_in, const int* in_sizes, int n_in,
                              void* d_out, int out_size, void* d_ws, size_t ws_size,
                              hipStream_t stream) {
    const float* pre = (const float*)d_in[0];   // (1,3,8192)
    const float* cur = (const float*)d_in[1];   // (1,3,16384)
    const float* ups = (const float*)d_in[2];   // (1,8192)
    float* out = (float*)d_out;                 // (1,8192)

    char* ws = (char*)d_ws;
    unsigned* c2p  = (unsigned*)ws;                        //  64 KB
    unsigned* top8 = (unsigned*)(ws + 65536);              // 256 KB
    float4*   pre4 = (float4*)(ws + 65536 + 262144);       // 128 KB
    float4*   cur4 = (float4*)(ws + 65536 + 262144 + 131072); // 256 KB

    prep_kernel<<<N_CUR / 256, 256, 0, stream>>>(pre, cur, pre4, cur4);

    fused_kernel<<<A_BLOCKS + B_BLOCKS, 256, 0, stream>>>(pre4, cur4, c2p, top8);

    finalize_kernel<<<(N_PRE * KNN) / 256, 256, 0, stream>>>(
        pre4, cur4, ups, c2p, top8, out);
}

// Round 8
// 154.513 us; speedup vs baseline: 1.4520x; 1.4520x over previous
//
#include <hip/hip_runtime.h>

// Problem constants (fixed by reference setup_inputs)
#define N_PRE 8192
#define N_CUR 16384
#define KNN   8

// Grid-accelerated EXACT kNN:
//  - counting-sort pre & cur into a 16^3 grid (cell h=0.625 over [-5,5))
//  - chunks = 64 consecutive sorted points; per-chunk AABB precomputed
//  - query wave tests chunk AABB lower bounds (12 ops per 64 candidates),
//    scans chunks outward from the query's cell, fully evaluates only
//    passing chunks. Exact: lb is a true lower bound (x0.999999 guards fp
//    rounding), u64 keys (dist_bits<<32|orig_idx) give exact tie-breaks.
//
// Workspace layout (bytes):
//   [0,    64K) : c2p    u32[N_CUR]
//   [64K, 320K) : top8   u32[N_PRE*8]
//   [320K,448K) : preS   float4[N_PRE]   sorted (x,y,z, bitcast orig idx)
//   [448K,704K) : curS   float4[N_CUR]
//   [704K,706K) : preBlo float4[128]
//   [706K,708K) : preBhi float4[128]
//   [708K,712K) : curBlo float4[256]
//   [712K,716K) : curBhi float4[256]
//   [716K,732K) : histP  u32[4096]   (memset 0 each launch)
//   [732K,748K) : histC  u32[4096]   (memset 0 each launch)
//   [748K,764K) : startP u32[4096]
//   [764K,780K) : startC u32[4096]
//   [780K,796K) : curP   u32[4096]   (scatter cursors, init by scan)
//   [796K,812K) : curC   u32[4096]

#define GRID_N 16
#define NCELL  4096
#define H_INV  1.6f
#define PRE_CHUNKS 128
#define CUR_CHUNKS 256
#define LB_SCALE 0.999999f
#define LIST_EMPTY 0x7F800000FFFFFFFFull  // key of +inf (NOT NaN — r2 lesson)

__device__ __forceinline__ int cell_of(float x, float y, float z) {
    int cx = (int)floorf((x + 5.f) * H_INV);
    int cy = (int)floorf((y + 5.f) * H_INV);
    int cz = (int)floorf((z + 5.f) * H_INV);
    cx = min(max(cx, 0), GRID_N - 1);
    cy = min(max(cy, 0), GRID_N - 1);
    cz = min(max(cz, 0), GRID_N - 1);
    return (cz * GRID_N + cy) * GRID_N + cx;
}
__device__ __forceinline__ unsigned long long shfl_u64(unsigned long long x, int src) {
    int lo = __shfl((int)(unsigned)x, src);
    int hi = __shfl((int)(unsigned)(x >> 32), src);
    return (((unsigned long long)(unsigned)hi) << 32) | (unsigned)lo;
}
__device__ __forceinline__ unsigned long long shfl_up1_u64(unsigned long long x) {
    int lo = __shfl_up((int)(unsigned)x, 1);
    int hi = __shfl_up((int)(unsigned)(x >> 32), 1);
    return (((unsigned long long)(unsigned)hi) << 32) | (unsigned)lo;
}

// ---------- stage 1: per-cell histogram ----------
__global__ __launch_bounds__(256) void count_kernel(
        const float* __restrict__ pre, const float* __restrict__ cur,
        unsigned* __restrict__ histP, unsigned* __restrict__ histC) {
    int i = blockIdx.x * 256 + threadIdx.x;
    if (i < N_CUR)
        atomicAdd(&histC[cell_of(cur[i], cur[N_CUR + i], cur[2 * N_CUR + i])], 1u);
    if (i < N_PRE)
        atomicAdd(&histP[cell_of(pre[i], pre[N_PRE + i], pre[2 * N_PRE + i])], 1u);
}

// ---------- stage 2: exclusive scan (single block) ----------
__device__ void scan4096(const unsigned* __restrict__ hist,
                         unsigned* __restrict__ start,
                         unsigned* __restrict__ cursor,
                         unsigned* a, unsigned* b) {
    int t = threadIdx.x;
#pragma unroll
    for (int i = 0; i < 4; ++i) a[t * 4 + i] = hist[t * 4 + i];
    __syncthreads();
    for (int stride = 1; stride < NCELL; stride <<= 1) {
#pragma unroll
        for (int i = 0; i < 4; ++i) {
            int idx = t * 4 + i;
            unsigned v = a[idx];
            if (idx >= stride) v += a[idx - stride];
            b[idx] = v;
        }
        __syncthreads();
        unsigned* tmp = a; a = b; b = tmp;
    }
#pragma unroll
    for (int i = 0; i < 4; ++i) {
        int idx = t * 4 + i;
        unsigned e = idx ? a[idx - 1] : 0u;
        start[idx] = e;
        cursor[idx] = e;
    }
}
__global__ __launch_bounds__(1024) void scan_kernel(
        const unsigned* __restrict__ histP, const unsigned* __restrict__ histC,
        unsigned* __restrict__ startP, unsigned* __restrict__ startC,
        unsigned* __restrict__ curP, unsigned* __restrict__ curC) {
    __shared__ unsigned a[NCELL], b[NCELL];
    scan4096(histP, startP, curP, a, b);
    __syncthreads();
    scan4096(histC, startC, curC, a, b);
}

// ---------- stage 3: scatter into sorted order ----------
__global__ __launch_bounds__(256) void scatter_kernel(
        const float* __restrict__ pre, const float* __restrict__ cur,
        unsigned* __restrict__ curP, unsigned* __restrict__ curC,
        float4* __restrict__ preS, float4* __restrict__ curS) {
    int i = blockIdx.x * 256 + threadIdx.x;
    if (i < N_CUR) {
        float x = cur[i], y = cur[N_CUR + i], z = cur[2 * N_CUR + i];
        unsigned pos = atomicAdd(&curC[cell_of(x, y, z)], 1u);
        curS[pos] = make_float4(x, y, z, __uint_as_float((unsigned)i));
    }
    if (i < N_PRE) {
        float x = pre[i], y = pre[N_PRE + i], z = pre[2 * N_PRE + i];
        unsigned pos = atomicAdd(&curP[cell_of(x, y, z)], 1u);
        preS[pos] = make_float4(x, y, z, __uint_as_float((unsigned)i));
    }
}

// ---------- stage 4: per-chunk AABB (one wave per chunk) ----------
__global__ __launch_bounds__(256) void aabb_kernel(
        const float4* __restrict__ preS, const float4* __restrict__ curS,
        float4* __restrict__ preBlo, float4* __restrict__ preBhi,
        float4* __restrict__ curBlo, float4* __restrict__ curBhi) {
    int g    = blockIdx.x * 4 + (threadIdx.x >> 6);
    int lane = threadIdx.x & 63;
    const float4* src; float4 *plo, *phi; int cid;
    if (g < PRE_CHUNKS) { src = preS; plo = preBlo; phi = preBhi; cid = g; }
    else                { src = curS; plo = curBlo; phi = curBhi; cid = g - PRE_CHUNKS; }
    float4 p = src[cid * 64 + lane];
    float mnx = p.x, mxx = p.x, mny = p.y, mxy = p.y, mnz = p.z, mxz = p.z;
#pragma unroll
    for (int o = 32; o > 0; o >>= 1) {
        mnx = fminf(mnx, __shfl_xor(mnx, o));  mxx = fmaxf(mxx, __shfl_xor(mxx, o));
        mny = fminf(mny, __shfl_xor(mny, o));  mxy = fmaxf(mxy, __shfl_xor(mxy, o));
        mnz = fminf(mnz, __shfl_xor(mnz, o));  mxz = fmaxf(mxz, __shfl_xor(mxz, o));
    }
    if (lane == 0) {
        plo[cid] = make_float4(mnx, mny, mnz, 0.f);
        phi[cid] = make_float4(mxx, mxy, mxz, 0.f);
    }
}

// ---------- kernel A: 1-NN cur -> pre (chunk-pruned exact) ----------
__global__ __launch_bounds__(256) void knn1_kernel(
        const float4* __restrict__ preS, const float4* __restrict__ curS,
        const float4* __restrict__ preBlo, const float4* __restrict__ preBhi,
        const unsigned* __restrict__ startP,
        unsigned* __restrict__ c2p) {
    const int lane  = threadIdx.x & 63;
    const int w     = threadIdx.x >> 6;
    const int qbase = (blockIdx.x * 4 + w) * 4;   // 4 sorted cur queries/wave

    float4 q[4];
#pragma unroll
    for (int t = 0; t < 4; ++t) q[t] = curS[qbase + t];

    unsigned long long bv[4];
    float tf[4];
#pragma unroll
    for (int t = 0; t < 4; ++t) { bv[t] = ~0ull; tf[t] = __int_as_float(0x7F800000); }

    const int c0 = (int)(startP[cell_of(q[0].x, q[0].y, q[0].z)] >> 6);

    for (int s = 0; s < PRE_CHUNKS; s += 64) {
        int r   = s + lane;                        // outward rank
        int off = (r + 1) >> 1;
        int cid = ((r & 1) ? (c0 + off) : (c0 - off)) & (PRE_CHUNKS - 1);
        float4 lo = preBlo[cid], hi = preBhi[cid];
        float lb[4];
        unsigned long long m[4];
#pragma unroll
        for (int t = 0; t < 4; ++t) {
            float dx = fmaxf(fmaxf(lo.x - q[t].x, q[t].x - hi.x), 0.f);
            float dy = fmaxf(fmaxf(lo.y - q[t].y, q[t].y - hi.y), 0.f);
            float dz = fmaxf(fmaxf(lo.z - q[t].z, q[t].z - hi.z), 0.f);
            lb[t] = fmaf(dx, dx, fmaf(dy, dy, dz * dz)) * LB_SCALE;
            m[t]  = __ballot(lb[t] < tf[t]);
        }
        unsigned long long mu = m[0] | m[1] | m[2] | m[3];
        while (mu) {                               // wave-uniform
            int src = __ffsll((long long)mu) - 1;  // lowest rank = nearest
            mu &= mu - 1;
            int cc = __shfl(cid, src);
            float4 cand = preS[cc * 64 + lane];
            unsigned oj = __float_as_uint(cand.w); // orig pre idx
#pragma unroll
            for (int t = 0; t < 4; ++t) {
                if ((m[t] >> src) & 1) {
                    float dx = q[t].x - cand.x, dy = q[t].y - cand.y, dz = q[t].z - cand.z;
                    float d = fmaf(dx, dx, fmaf(dy, dy, dz * dz));
                    unsigned long long dk =
                        (((unsigned long long)__float_as_uint(d)) << 32) | oj;
                    if (__ballot(dk < bv[t])) {
                        unsigned long long v = dk;
#pragma unroll
                        for (int o = 32; o > 0; o >>= 1) {
                            unsigned long long x = __shfl_xor((unsigned long long)v, o);
                            v = (x < v) ? x : v;
                        }
                        bv[t] = v;
                        tf[t] = __uint_as_float((unsigned)(v >> 32));
                    }
                }
            }
#pragma unroll
            for (int t = 0; t < 4; ++t) m[t] &= __ballot(lb[t] < tf[t]);
            mu &= (m[0] | m[1] | m[2] | m[3]);
        }
    }
#pragma unroll
    for (int t = 0; t < 4; ++t)
        if (lane == 0)
            c2p[__float_as_uint(q[t].w)] = (unsigned)(bv[t] & 0xFFFFFFFFull);
}

// ---------- kernel B: top-8 pre -> cur (chunk-pruned exact) ----------
__global__ __launch_bounds__(256) void knn8_kernel(
        const float4* __restrict__ preS, const float4* __restrict__ curS,
        const float4* __restrict__ curBlo, const float4* __restrict__ curBhi,
        const unsigned* __restrict__ startC,
        unsigned* __restrict__ top8) {
    const int lane  = threadIdx.x & 63;
    const int w     = threadIdx.x >> 6;
    const int qbase = (blockIdx.x * 4 + w) * 2;   // 2 sorted pre queries/wave

    const float4 q0 = preS[qbase], q1 = preS[qbase + 1];

    unsigned long long l0 = LIST_EMPTY, l1 = LIST_EMPTY;   // lanes 0..7 sorted
    unsigned long long k80 = LIST_EMPTY, k81 = LIST_EMPTY; // 8th key (uniform)
    float tf0 = __int_as_float(0x7F800000), tf1 = tf0;

    const int c0 = (int)(startC[cell_of(q0.x, q0.y, q0.z)] >> 6);

    for (int s = 0; s < CUR_CHUNKS; s += 64) {
        int r   = s + lane;
        int off = (r + 1) >> 1;
        int cid = ((r & 1) ? (c0 + off) : (c0 - off)) & (CUR_CHUNKS - 1);
        float4 lo = curBlo[cid], hi = curBhi[cid];
        float dx0 = fmaxf(fmaxf(lo.x - q0.x, q0.x - hi.x), 0.f);
        float dy0 = fmaxf(fmaxf(lo.y - q0.y, q0.y - hi.y), 0.f);
        float dz0 = fmaxf(fmaxf(lo.z - q0.z, q0.z - hi.z), 0.f);
        float lb0 = fmaf(dx0, dx0, fmaf(dy0, dy0, dz0 * dz0)) * LB_SCALE;
        float dx1 = fmaxf(fmaxf(lo.x - q1.x, q1.x - hi.x), 0.f);
        float dy1 = fmaxf(fmaxf(lo.y - q1.y, q1.y - hi.y), 0.f);
        float dz1 = fmaxf(fmaxf(lo.z - q1.z, q1.z - hi.z), 0.f);
        float lb1 = fmaf(dx1, dx1, fmaf(dy1, dy1, dz1 * dz1)) * LB_SCALE;

        unsigned long long m0 = __ballot(lb0 < tf0);
        unsigned long long m1 = __ballot(lb1 < tf1);
        unsigned long long mu = m0 | m1;
        while (mu) {
            int src = __ffsll((long long)mu) - 1;
            mu &= mu - 1;
            int cc = __shfl(cid, src);
            float4 cand = curS[cc * 64 + lane];
            unsigned oj = __float_as_uint(cand.w);  // orig cur idx
            if ((m0 >> src) & 1) {
                float dx = q0.x - cand.x, dy = q0.y - cand.y, dz = q0.z - cand.z;
                float d = fmaf(dx, dx, fmaf(dy, dy, dz * dz));
                unsigned long long dk =
                    (((unsigned long long)__float_as_uint(d)) << 32) | oj;
                unsigned long long mm = __ballot(dk < k80);
                while (mm) {
                    int sl = __ffsll((long long)mm) - 1;
                    unsigned long long v  = shfl_u64(dk, sl);
                    unsigned long long up = shfl_up1_u64(l0);
                    if (lane == 0) up = 0ull;
                    bool hi_ = v < up, lo_ = v < l0;
                    l0  = hi_ ? up : (lo_ ? v : l0);
                    k80 = shfl_u64(l0, 7);
                    tf0 = __uint_as_float((unsigned)(k80 >> 32));
                    mm = (mm & (mm - 1)) & __ballot(dk < k80);
                }
            }
            if ((m1 >> src) & 1) {
                float dx = q1.x - cand.x, dy = q1.y - cand.y, dz = q1.z - cand.z;
                float d = fmaf(dx, dx, fmaf(dy, dy, dz * dz));
                unsigned long long dk =
                    (((unsigned long long)__float_as_uint(d)) << 32) | oj;
                unsigned long long mm = __ballot(dk < k81);
                while (mm) {
                    int sl = __ffsll((long long)mm) - 1;
                    unsigned long long v  = shfl_u64(dk, sl);
                    unsigned long long up = shfl_up1_u64(l1);
                    if (lane == 0) up = 0ull;
                    bool hi_ = v < up, lo_ = v < l1;
                    l1  = hi_ ? up : (lo_ ? v : l1);
                    k81 = shfl_u64(l1, 7);
                    tf1 = __uint_as_float((unsigned)(k81 >> 32));
                    mm = (mm & (mm - 1)) & __ballot(dk < k81);
                }
            }
            m0 &= __ballot(lb0 < tf0);
            m1 &= __ballot(lb1 < tf1);
            mu &= (m0 | m1);
        }
    }
    if (lane < 8) {
        top8[__float_as_uint(q0.w) * 8 + lane] = (unsigned)(l0 & 0xFFFFFFFFull);
        top8[__float_as_uint(q1.w) * 8 + lane] = (unsigned)(l1 & 0xFFFFFFFFull);
    }
}

// ---------- finalize: mask + sqrt + mean ----------
__global__ __launch_bounds__(256) void finalize_kernel(
        const float* __restrict__ pre, const float* __restrict__ cur,
        const float* __restrict__ ups,
        const unsigned* __restrict__ c2p, const unsigned* __restrict__ top8,
        float* __restrict__ out) {
    int gid = blockIdx.x * 256 + threadIdx.x;
    int i = gid >> 3;
    unsigned j = top8[gid];
    float dx = cur[j]             - pre[i];
    float dy = cur[N_CUR + j]     - pre[N_PRE + i];
    float dz = cur[2 * N_CUR + j] - pre[2 * N_PRE + i];
    float dsq = fmaf(dx, dx, fmaf(dy, dy, dz * dz));
    float v = (c2p[j] == (unsigned)i) ? sqrtf(dsq) : 0.f;
    v += __shfl_xor(v, 1);
    v += __shfl_xor(v, 2);
    v += __shfl_xor(v, 4);
    if ((gid & 7) == 0) out[i] = v / ups[i];
}

// ---------- launch ----------
extern "C" void kernel_launch(void* const* d_in, const int* in_sizes, int n_in,
                              void* d_out, int out_size, void* d_ws, size_t ws_size,
                              hipStream_t stream) {
    const float* pre = (const float*)d_in[0];   // (1,3,8192)
    const float* cur = (const float*)d_in[1];   // (1,3,16384)
    const float* ups = (const float*)d_in[2];   // (1,8192)
    float* out = (float*)d_out;                 // (1,8192)

    char* ws = (char*)d_ws;
    unsigned* c2p    = (unsigned*)(ws + 0);
    unsigned* top8   = (unsigned*)(ws + (64u << 10));
    float4*   preS   = (float4*)  (ws + (320u << 10));
    float4*   curS   = (float4*)  (ws + (448u << 10));
    float4*   preBlo = (float4*)  (ws + (704u << 10));
    float4*   preBhi = (float4*)  (ws + (706u << 10));
    float4*   curBlo = (float4*)  (ws + (708u << 10));
    float4*   curBhi = (float4*)  (ws + (712u << 10));
    unsigned* histP  = (unsigned*)(ws + (716u << 10));
    unsigned* histC  = (unsigned*)(ws + (732u << 10));
    unsigned* startP = (unsigned*)(ws + (748u << 10));
    unsigned* startC = (unsigned*)(ws + (764u << 10));
    unsigned* curP   = (unsigned*)(ws + (780u << 10));
    unsigned* curC   = (unsigned*)(ws + (796u << 10));

    hipMemsetAsync(histP, 0, 2 * NCELL * sizeof(unsigned), stream);  // histP+histC

    count_kernel<<<N_CUR / 256, 256, 0, stream>>>(pre, cur, histP, histC);
    scan_kernel<<<1, 1024, 0, stream>>>(histP, histC, startP, startC, curP, curC);
    scatter_kernel<<<N_CUR / 256, 256, 0, stream>>>(pre, cur, curP, curC, preS, curS);
    aabb_kernel<<<(PRE_CHUNKS + CUR_CHUNKS) / 4, 256, 0, stream>>>(
        preS, curS, preBlo, preBhi, curBlo, curBhi);

    knn1_kernel<<<N_CUR / 16, 256, 0, stream>>>(preS, curS, preBlo, preBhi, startP, c2p);
    knn8_kernel<<<N_PRE / 8, 256, 0, stream>>>(preS, curS, curBlo, curBhi, startC, top8);

    finalize_kernel<<<(N_PRE * KNN) / 256, 256, 0, stream>>>(
        pre, cur, ups, c2p, top8, out);
}

// Round 9
// 148.742 us; speedup vs baseline: 1.5083x; 1.0388x over previous
//
#include <hip/hip_runtime.h>

// Problem constants (fixed by reference setup_inputs)
#define N_PRE 8192
#define N_CUR 16384
#define KNN   8

// Grid-accelerated EXACT kNN (round-8 algorithm, round-9 latency fixes):
//  - counting-sort pre & cur into a 16^3 grid; chunks = 64 sorted points
//  - per-chunk AABB; query wave tests all chunk AABBs (outward order from
//    the query's own cell), fully evaluates only passing chunks
//  - exact: lb is a true lower bound (x0.999999 fp guard); u64 keys
//    (dist_bits<<32|orig_idx) give exact argmin/top-k tie-breaks
//  - r9: knn1+knn8 fused in ONE dispatch (role by blockIdx parity) for 2x
//    resident waves; candidate gathers software-pipelined (prefetch next
//    passing chunk before processing current); 2-barrier wave-scan.
//
// Workspace layout (bytes):
//   [0,    64K) : c2p    u32[N_CUR]
//   [64K, 320K) : top8   u32[N_PRE*8]
//   [320K,448K) : preS   float4[N_PRE]   sorted (x,y,z, bitcast orig idx)
//   [448K,704K) : curS   float4[N_CUR]
//   [704K,706K) : preBlo float4[128]
//   [706K,708K) : preBhi float4[128]
//   [708K,712K) : curBlo float4[256]
//   [712K,716K) : curBhi float4[256]
//   [716K,732K) : histP  u32[4096]   (memset 0 each launch)
//   [732K,748K) : histC  u32[4096]   (memset 0 each launch)
//   [748K,764K) : startP u32[4096]
//   [764K,780K) : startC u32[4096]
//   [780K,796K) : curP   u32[4096]   (scatter cursors)
//   [796K,812K) : curC   u32[4096]

#define GRID_N 16
#define NCELL  4096
#define H_INV  1.6f
#define PRE_CHUNKS 128
#define CUR_CHUNKS 256
#define LB_SCALE 0.999999f
#define LIST_EMPTY 0x7F800000FFFFFFFFull  // key of +inf (NOT NaN — r2 lesson)

__device__ __forceinline__ int cell_of(float x, float y, float z) {
    int cx = (int)floorf((x + 5.f) * H_INV);
    int cy = (int)floorf((y + 5.f) * H_INV);
    int cz = (int)floorf((z + 5.f) * H_INV);
    cx = min(max(cx, 0), GRID_N - 1);
    cy = min(max(cy, 0), GRID_N - 1);
    cz = min(max(cz, 0), GRID_N - 1);
    return (cz * GRID_N + cy) * GRID_N + cx;
}
__device__ __forceinline__ unsigned long long shfl_u64(unsigned long long x, int src) {
    int lo = __shfl((int)(unsigned)x, src);
    int hi = __shfl((int)(unsigned)(x >> 32), src);
    return (((unsigned long long)(unsigned)hi) << 32) | (unsigned)lo;
}
__device__ __forceinline__ unsigned long long shfl_up1_u64(unsigned long long x) {
    int lo = __shfl_up((int)(unsigned)x, 1);
    int hi = __shfl_up((int)(unsigned)(x >> 32), 1);
    return (((unsigned long long)(unsigned)hi) << 32) | (unsigned)lo;
}

// ---------- stage 1: per-cell histogram ----------
__global__ __launch_bounds__(256) void count_kernel(
        const float* __restrict__ pre, const float* __restrict__ cur,
        unsigned* __restrict__ histP, unsigned* __restrict__ histC) {
    int i = blockIdx.x * 256 + threadIdx.x;
    if (i < N_CUR)
        atomicAdd(&histC[cell_of(cur[i], cur[N_CUR + i], cur[2 * N_CUR + i])], 1u);
    if (i < N_PRE)
        atomicAdd(&histP[cell_of(pre[i], pre[N_PRE + i], pre[2 * N_PRE + i])], 1u);
}

// ---------- stage 2: exclusive scan, 2 barriers (wave-scan) ----------
__device__ __forceinline__ void scan4096_fast(
        const unsigned* __restrict__ hist,
        unsigned* __restrict__ start, unsigned* __restrict__ cursor,
        unsigned* waveTot, unsigned* waveOff) {
    const int t = threadIdx.x, lane = t & 63, w = t >> 6;
    unsigned v0 = hist[t * 4], v1 = hist[t * 4 + 1];
    unsigned v2 = hist[t * 4 + 2], v3 = hist[t * 4 + 3];
    unsigned own = v0 + v1 + v2 + v3;
    unsigned incl = own;
#pragma unroll
    for (int off = 1; off < 64; off <<= 1) {
        unsigned u = (unsigned)__shfl_up((int)incl, off);
        if (lane >= off) incl += u;
    }
    if (lane == 63) waveTot[w] = incl;
    __syncthreads();
    if (t == 0) {
        unsigned run = 0;
        for (int i = 0; i < 16; ++i) { unsigned x = waveTot[i]; waveOff[i] = run; run += x; }
    }
    __syncthreads();
    unsigned e = waveOff[w] + incl - own;
    start[t * 4]     = e; cursor[t * 4]     = e; e += v0;
    start[t * 4 + 1] = e; cursor[t * 4 + 1] = e; e += v1;
    start[t * 4 + 2] = e; cursor[t * 4 + 2] = e; e += v2;
    start[t * 4 + 3] = e; cursor[t * 4 + 3] = e;
}
__global__ __launch_bounds__(1024) void scan_kernel(
        const unsigned* __restrict__ histP, const unsigned* __restrict__ histC,
        unsigned* __restrict__ startP, unsigned* __restrict__ startC,
        unsigned* __restrict__ curP, unsigned* __restrict__ curC) {
    __shared__ unsigned waveTot[16], waveOff[16];
    scan4096_fast(histP, startP, curP, waveTot, waveOff);
    __syncthreads();
    scan4096_fast(histC, startC, curC, waveTot, waveOff);
}

// ---------- stage 3: scatter into sorted order ----------
__global__ __launch_bounds__(256) void scatter_kernel(
        const float* __restrict__ pre, const float* __restrict__ cur,
        unsigned* __restrict__ curP, unsigned* __restrict__ curC,
        float4* __restrict__ preS, float4* __restrict__ curS) {
    int i = blockIdx.x * 256 + threadIdx.x;
    if (i < N_CUR) {
        float x = cur[i], y = cur[N_CUR + i], z = cur[2 * N_CUR + i];
        unsigned pos = atomicAdd(&curC[cell_of(x, y, z)], 1u);
        curS[pos] = make_float4(x, y, z, __uint_as_float((unsigned)i));
    }
    if (i < N_PRE) {
        float x = pre[i], y = pre[N_PRE + i], z = pre[2 * N_PRE + i];
        unsigned pos = atomicAdd(&curP[cell_of(x, y, z)], 1u);
        preS[pos] = make_float4(x, y, z, __uint_as_float((unsigned)i));
    }
}

// ---------- stage 4: per-chunk AABB (one wave per chunk) ----------
__global__ __launch_bounds__(256) void aabb_kernel(
        const float4* __restrict__ preS, const float4* __restrict__ curS,
        float4* __restrict__ preBlo, float4* __restrict__ preBhi,
        float4* __restrict__ curBlo, float4* __restrict__ curBhi) {
    int g    = blockIdx.x * 4 + (threadIdx.x >> 6);
    int lane = threadIdx.x & 63;
    const float4* src; float4 *plo, *phi; int cid;
    if (g < PRE_CHUNKS) { src = preS; plo = preBlo; phi = preBhi; cid = g; }
    else                { src = curS; plo = curBlo; phi = curBhi; cid = g - PRE_CHUNKS; }
    float4 p = src[cid * 64 + lane];
    float mnx = p.x, mxx = p.x, mny = p.y, mxy = p.y, mnz = p.z, mxz = p.z;
#pragma unroll
    for (int o = 32; o > 0; o >>= 1) {
        mnx = fminf(mnx, __shfl_xor(mnx, o));  mxx = fmaxf(mxx, __shfl_xor(mxx, o));
        mny = fminf(mny, __shfl_xor(mny, o));  mxy = fmaxf(mxy, __shfl_xor(mxy, o));
        mnz = fminf(mnz, __shfl_xor(mnz, o));  mxz = fmaxf(mxz, __shfl_xor(mxz, o));
    }
    if (lane == 0) {
        plo[cid] = make_float4(mnx, mny, mnz, 0.f);
        phi[cid] = make_float4(mxx, mxy, mxz, 0.f);
    }
}

// ---------- fused knn1 + knn8 (role by blockIdx parity) ----------
__global__ __launch_bounds__(256) void knn_fused_kernel(
        const float4* __restrict__ preS, const float4* __restrict__ curS,
        const float4* __restrict__ preBlo, const float4* __restrict__ preBhi,
        const float4* __restrict__ curBlo, const float4* __restrict__ curBhi,
        const unsigned* __restrict__ startP, const unsigned* __restrict__ startC,
        unsigned* __restrict__ c2p, unsigned* __restrict__ top8) {
    const int lane = threadIdx.x & 63;
    const int w    = threadIdx.x >> 6;
    const int sub  = blockIdx.x >> 1;

    if ((blockIdx.x & 1) == 0) {
        // ============ role A: 1-NN cur -> pre, 4 queries/wave ============
        const int qbase = (sub * 4 + w) * 4;
        float4 q[4];
#pragma unroll
        for (int t = 0; t < 4; ++t) q[t] = curS[qbase + t];

        unsigned long long bv[4];
        float tf[4];
#pragma unroll
        for (int t = 0; t < 4; ++t) { bv[t] = ~0ull; tf[t] = __int_as_float(0x7F800000); }

        const int c0 = (int)(startP[cell_of(q[0].x, q[0].y, q[0].z)] >> 6);

        for (int s = 0; s < PRE_CHUNKS; s += 64) {
            int r   = s + lane;
            int off = (r + 1) >> 1;
            int cid = ((r & 1) ? (c0 + off) : (c0 - off)) & (PRE_CHUNKS - 1);
            float4 lo = preBlo[cid], hi = preBhi[cid];
            float lb[4];
            unsigned long long m[4];
#pragma unroll
            for (int t = 0; t < 4; ++t) {
                float dx = fmaxf(fmaxf(lo.x - q[t].x, q[t].x - hi.x), 0.f);
                float dy = fmaxf(fmaxf(lo.y - q[t].y, q[t].y - hi.y), 0.f);
                float dz = fmaxf(fmaxf(lo.z - q[t].z, q[t].z - hi.z), 0.f);
                lb[t] = fmaf(dx, dx, fmaf(dy, dy, dz * dz)) * LB_SCALE;
                m[t]  = __ballot(lb[t] < tf[t]);
            }
            unsigned long long mu = m[0] | m[1] | m[2] | m[3];

            // software pipeline: pop + prefetch next chunk before processing
            int srcn = -1; float4 candn;
            if (mu) {
                srcn = __ffsll((long long)mu) - 1;
                mu &= ~(1ull << srcn);
                int cc = __shfl(cid, srcn);
                candn = preS[cc * 64 + lane];
            }
            while (srcn >= 0) {
                int src = srcn; float4 cand = candn;
                if (mu) {
                    srcn = __ffsll((long long)mu) - 1;
                    mu &= ~(1ull << srcn);
                    int cc = __shfl(cid, srcn);
                    candn = preS[cc * 64 + lane];
                } else srcn = -1;

                unsigned oj = __float_as_uint(cand.w);
#pragma unroll
                for (int t = 0; t < 4; ++t) {
                    if ((m[t] >> src) & 1) {
                        float dx = q[t].x - cand.x, dy = q[t].y - cand.y, dz = q[t].z - cand.z;
                        float d = fmaf(dx, dx, fmaf(dy, dy, dz * dz));
                        unsigned long long dk =
                            (((unsigned long long)__float_as_uint(d)) << 32) | oj;
                        if (__ballot(dk < bv[t])) {
                            unsigned long long v = dk;
#pragma unroll
                            for (int o = 32; o > 0; o >>= 1) {
                                unsigned long long x = __shfl_xor((unsigned long long)v, o);
                                v = (x < v) ? x : v;
                            }
                            bv[t] = v;
                            tf[t] = __uint_as_float((unsigned)(v >> 32));
                        }
                    }
                }
#pragma unroll
                for (int t = 0; t < 4; ++t) m[t] &= __ballot(lb[t] < tf[t]);
                mu &= (m[0] | m[1] | m[2] | m[3]);
            }
        }
#pragma unroll
        for (int t = 0; t < 4; ++t)
            if (lane == 0)
                c2p[__float_as_uint(q[t].w)] = (unsigned)(bv[t] & 0xFFFFFFFFull);

    } else {
        // ============ role B: top-8 pre -> cur, 2 queries/wave ============
        const int qbase = (sub * 4 + w) * 2;
        const float4 q0 = preS[qbase], q1 = preS[qbase + 1];

        unsigned long long l0 = LIST_EMPTY, l1 = LIST_EMPTY;   // lanes 0..7
        unsigned long long k80 = LIST_EMPTY, k81 = LIST_EMPTY; // 8th key
        float tf0 = __int_as_float(0x7F800000), tf1 = tf0;

        const int c0 = (int)(startC[cell_of(q0.x, q0.y, q0.z)] >> 6);

        for (int s = 0; s < CUR_CHUNKS; s += 64) {
            int r   = s + lane;
            int off = (r + 1) >> 1;
            int cid = ((r & 1) ? (c0 + off) : (c0 - off)) & (CUR_CHUNKS - 1);
            float4 lo = curBlo[cid], hi = curBhi[cid];
            float dx0 = fmaxf(fmaxf(lo.x - q0.x, q0.x - hi.x), 0.f);
            float dy0 = fmaxf(fmaxf(lo.y - q0.y, q0.y - hi.y), 0.f);
            float dz0 = fmaxf(fmaxf(lo.z - q0.z, q0.z - hi.z), 0.f);
            float lb0 = fmaf(dx0, dx0, fmaf(dy0, dy0, dz0 * dz0)) * LB_SCALE;
            float dx1 = fmaxf(fmaxf(lo.x - q1.x, q1.x - hi.x), 0.f);
            float dy1 = fmaxf(fmaxf(lo.y - q1.y, q1.y - hi.y), 0.f);
            float dz1 = fmaxf(fmaxf(lo.z - q1.z, q1.z - hi.z), 0.f);
            float lb1 = fmaf(dx1, dx1, fmaf(dy1, dy1, dz1 * dz1)) * LB_SCALE;

            unsigned long long m0 = __ballot(lb0 < tf0);
            unsigned long long m1 = __ballot(lb1 < tf1);
            unsigned long long mu = m0 | m1;

            int srcn = -1; float4 candn;
            if (mu) {
                srcn = __ffsll((long long)mu) - 1;
                mu &= ~(1ull << srcn);
                int cc = __shfl(cid, srcn);
                candn = curS[cc * 64 + lane];
            }
            while (srcn >= 0) {
                int src = srcn; float4 cand = candn;
                if (mu) {
                    srcn = __ffsll((long long)mu) - 1;
                    mu &= ~(1ull << srcn);
                    int cc = __shfl(cid, srcn);
                    candn = curS[cc * 64 + lane];
                } else srcn = -1;

                unsigned oj = __float_as_uint(cand.w);
                if ((m0 >> src) & 1) {
                    float dx = q0.x - cand.x, dy = q0.y - cand.y, dz = q0.z - cand.z;
                    float d = fmaf(dx, dx, fmaf(dy, dy, dz * dz));
                    unsigned long long dk =
                        (((unsigned long long)__float_as_uint(d)) << 32) | oj;
                    unsigned long long mm = __ballot(dk < k80);
                    while (mm) {
                        int sl = __ffsll((long long)mm) - 1;
                        unsigned long long v  = shfl_u64(dk, sl);
                        unsigned long long up = shfl_up1_u64(l0);
                        if (lane == 0) up = 0ull;
                        bool hi_ = v < up, lo_ = v < l0;
                        l0  = hi_ ? up : (lo_ ? v : l0);
                        k80 = shfl_u64(l0, 7);
                        tf0 = __uint_as_float((unsigned)(k80 >> 32));
                        mm = (mm & (mm - 1)) & __ballot(dk < k80);
                    }
                }
                if ((m1 >> src) & 1) {
                    float dx = q1.x - cand.x, dy = q1.y - cand.y, dz = q1.z - cand.z;
                    float d = fmaf(dx, dx, fmaf(dy, dy, dz * dz));
                    unsigned long long dk =
                        (((unsigned long long)__float_as_uint(d)) << 32) | oj;
                    unsigned long long mm = __ballot(dk < k81);
                    while (mm) {
                        int sl = __ffsll((long long)mm) - 1;
                        unsigned long long v  = shfl_u64(dk, sl);
                        unsigned long long up = shfl_up1_u64(l1);
                        if (lane == 0) up = 0ull;
                        bool hi_ = v < up, lo_ = v < l1;
                        l1  = hi_ ? up : (lo_ ? v : l1);
                        k81 = shfl_u64(l1, 7);
                        tf1 = __uint_as_float((unsigned)(k81 >> 32));
                        mm = (mm & (mm - 1)) & __ballot(dk < k81);
                    }
                }
                m0 &= __ballot(lb0 < tf0);
                m1 &= __ballot(lb1 < tf1);
                mu &= (m0 | m1);
            }
        }
        if (lane < 8) {
            top8[__float_as_uint(q0.w) * 8 + lane] = (unsigned)(l0 & 0xFFFFFFFFull);
            top8[__float_as_uint(q1.w) * 8 + lane] = (unsigned)(l1 & 0xFFFFFFFFull);
        }
    }
}

// ---------- finalize: mask + sqrt + mean ----------
__global__ __launch_bounds__(256) void finalize_kernel(
        const float* __restrict__ pre, const float* __restrict__ cur,
        const float* __restrict__ ups,
        const unsigned* __restrict__ c2p, const unsigned* __restrict__ top8,
        float* __restrict__ out) {
    int gid = blockIdx.x * 256 + threadIdx.x;
    int i = gid >> 3;
    unsigned j = top8[gid];
    float dx = cur[j]             - pre[i];
    float dy = cur[N_CUR + j]     - pre[N_PRE + i];
    float dz = cur[2 * N_CUR + j] - pre[2 * N_PRE + i];
    float dsq = fmaf(dx, dx, fmaf(dy, dy, dz * dz));
    float v = (c2p[j] == (unsigned)i) ? sqrtf(dsq) : 0.f;
    v += __shfl_xor(v, 1);
    v += __shfl_xor(v, 2);
    v += __shfl_xor(v, 4);
    if ((gid & 7) == 0) out[i] = v / ups[i];
}

// ---------- launch ----------
extern "C" void kernel_launch(void* const* d_in, const int* in_sizes, int n_in,
                              void* d_out, int out_size, void* d_ws, size_t ws_size,
                              hipStream_t stream) {
    const float* pre = (const float*)d_in[0];   // (1,3,8192)
    const float* cur = (const float*)d_in[1];   // (1,3,16384)
    const float* ups = (const float*)d_in[2];   // (1,8192)
    float* out = (float*)d_out;                 // (1,8192)

    char* ws = (char*)d_ws;
    unsigned* c2p    = (unsigned*)(ws + 0);
    unsigned* top8   = (unsigned*)(ws + (64u << 10));
    float4*   preS   = (float4*)  (ws + (320u << 10));
    float4*   curS   = (float4*)  (ws + (448u << 10));
    float4*   preBlo = (float4*)  (ws + (704u << 10));
    float4*   preBhi = (float4*)  (ws + (706u << 10));
    float4*   curBlo = (float4*)  (ws + (708u << 10));
    float4*   curBhi = (float4*)  (ws + (712u << 10));
    unsigned* histP  = (unsigned*)(ws + (716u << 10));
    unsigned* histC  = (unsigned*)(ws + (732u << 10));
    unsigned* startP = (unsigned*)(ws + (748u << 10));
    unsigned* startC = (unsigned*)(ws + (764u << 10));
    unsigned* curP   = (unsigned*)(ws + (780u << 10));
    unsigned* curC   = (unsigned*)(ws + (796u << 10));

    hipMemsetAsync(histP, 0, 2 * NCELL * sizeof(unsigned), stream);  // histP+histC

    count_kernel<<<N_CUR / 256, 256, 0, stream>>>(pre, cur, histP, histC);
    scan_kernel<<<1, 1024, 0, stream>>>(histP, histC, startP, startC, curP, curC);
    scatter_kernel<<<N_CUR / 256, 256, 0, stream>>>(pre, cur, curP, curC, preS, curS);
    aabb_kernel<<<(PRE_CHUNKS + CUR_CHUNKS) / 4, 256, 0, stream>>>(
        preS, curS, preBlo, preBhi, curBlo, curBhi);

    // fused: even blocks = knn1 (1024 subs), odd blocks = knn8 (1024 subs)
    knn_fused_kernel<<<2048, 256, 0, stream>>>(
        preS, curS, preBlo, preBhi, curBlo, curBhi, startP, startC, c2p, top8);

    finalize_kernel<<<(N_PRE * KNN) / 256, 256, 0, stream>>>(
        pre, cur, ups, c2p, top8, out);
}